// Round 2
// baseline (106.947 us; speedup 1.0000x reference)
//
#include <hip/hip_runtime.h>
#include <hip/hip_bf16.h>
#include <math.h>

#define NROWS 8192
#define DDIM  128
#define JCHUNKS 16
#define JPER  (NROWS / JCHUNKS)        // 512 cols per chunk
#define CT_TOTAL (JPER / 16)           // 32 column-tiles of 16
#define ROWS_PER_BLOCK 128             // 2 waves x 64 rows
#define GRIDX (NROWS / ROWS_PER_BLOCK) // 64
#define LOG2E 1.44269504088896f

typedef __attribute__((ext_vector_type(8))) short bf16x8;  // 8 bf16 = 4 VGPRs
typedef __attribute__((ext_vector_type(4))) float f32x4;

// ---------------- kernel 1: L2 row-normalize -> bf16 (also zeroes out[0]) ----------------
__global__ __launch_bounds__(256) void norm_kernel(
    const float* __restrict__ f1, const float* __restrict__ f2,
    __hip_bfloat16* __restrict__ f1b, __hip_bfloat16* __restrict__ f2b,
    float* __restrict__ out) {
  if (blockIdx.x == 0 && threadIdx.x == 0) out[0] = 0.0f;  // stream-ordered before finalize
  int t = threadIdx.x;
  int rloc = t >> 5;                 // 0..7
  int l = t & 31;
  int b = blockIdx.x;                // 0..2047
  int half = (b >= NROWS / 8) ? 1 : 0;
  int row = (b - half * (NROWS / 8)) * 8 + rloc;
  const float* src = half ? f2 : f1;
  __hip_bfloat16* dst = half ? f2b : f1b;

  float4 v = ((const float4*)src)[row * (DDIM / 4) + l];
  float s = v.x * v.x + v.y * v.y + v.z * v.z + v.w * v.w;
  #pragma unroll
  for (int off = 1; off < 32; off <<= 1) s += __shfl_xor(s, off, 64);
  float inv = 1.0f / fmaxf(sqrtf(s), 1e-12f);
  __hip_bfloat16 hv[4];
  hv[0] = __float2bfloat16(v.x * inv);
  hv[1] = __float2bfloat16(v.y * inv);
  hv[2] = __float2bfloat16(v.z * inv);
  hv[3] = __float2bfloat16(v.w * inv);
  *(ushort4*)&dst[(size_t)row * DDIM + l * 4] = *(ushort4*)hv;
}

// ---------------- kernel 2: MFMA cos grid, B read straight from L2 (no LDS, no barriers) ----------------
// f2b is 2 MB -> fully L2-resident; LDS staging was pure overhead (lockstep DMA-drain stalls).
// 64 rows/wave, 2-deep register ping-pong prefetch of B fragments + tj.
// partials[(row*JCHUNKS + chunk)*4 + {Z,Zp,Cp,Np}]
__global__ __launch_bounds__(128, 2) void stats_kernel(
    const __hip_bfloat16* __restrict__ f1b,
    const __hip_bfloat16* __restrict__ f2b,
    const float* __restrict__ targets,
    float* __restrict__ partials) {
  const int chunk = blockIdx.y;                  // 0..15
  const int i0 = blockIdx.x * ROWS_PER_BLOCK;
  const int w    = threadIdx.x >> 6;             // 0..1
  const int lane = threadIdx.x & 63;
  const int p15  = lane & 15;
  const int rl4  = lane >> 4;                    // quad
  const int rbase = i0 + w * 64;                 // this wave's 64 rows

  // ---- A fragments resident for whole sweep: A[m=p15][k = rl4*8 + ks*32 ..] ----
  bf16x8 afrag[4][4];
  #pragma unroll
  for (int rs = 0; rs < 4; ++rs) {
    const __hip_bfloat16* arow =
        &f1b[(size_t)(rbase + rs * 16 + p15) * DDIM + rl4 * 8];
    #pragma unroll
    for (int ks = 0; ks < 4; ++ks)
      afrag[rs][ks] = *(const bf16x8*)(arow + ks * 32);
  }

  // lane's C rows per rs: row = rbase + rs*16 + rl4*4 + rr  (reg rr of acc[rs])
  f32x4 ki[4];
  #pragma unroll
  for (int rs = 0; rs < 4; ++rs)
    #pragma unroll
    for (int rr = 0; rr < 4; ++rr)
      ki[rs][rr] = targets[rbase + rs * 16 + rl4 * 4 + rr];

  f32x4 Z[4], Zp[4], Cp[4], Np[4];
  #pragma unroll
  for (int rs = 0; rs < 4; ++rs) {
    Z[rs] = (f32x4){0.f, 0.f, 0.f, 0.f};
    Zp[rs] = (f32x4){0.f, 0.f, 0.f, 0.f};
    Cp[rs] = (f32x4){0.f, 0.f, 0.f, 0.f};
    Np[rs] = (f32x4){0.f, 0.f, 0.f, 0.f};
  }

  const int jb0 = chunk * JPER;
  // lane's B base: col (jb0 + ct*16 + p15), k-offset rl4*8 (+ks*32)
  const __hip_bfloat16* bptr = f2b + (size_t)(jb0 + p15) * DDIM + rl4 * 8;
  const float* tptr = targets + jb0 + p15;

  // ---- prefetch macro: fragment + tj for column-tile ct ----
  #define LOADB(BF, TJ, CT)                                                 \
    do {                                                                    \
      const __hip_bfloat16* _p = bptr + (size_t)(CT) * 16 * DDIM;           \
      _Pragma("unroll")                                                     \
      for (int _ks = 0; _ks < 4; ++_ks)                                     \
        (BF)[_ks] = *(const bf16x8*)(_p + _ks * 32);                        \
      (TJ) = tptr[(CT) * 16];                                               \
    } while (0)

  #define COMPUTE(BF, TJ)                                                   \
    do {                                                                    \
      const float _tj = (TJ);                                               \
      const bool _pj = _tj > 0.0f;                                          \
      const f32x4 _tj4 = {_tj, _tj, _tj, _tj};                              \
      const f32x4 _K4  = {LOG2E, LOG2E, LOG2E, LOG2E};                      \
      _Pragma("unroll")                                                     \
      for (int _rs = 0; _rs < 4; ++_rs) {                                   \
        f32x4 _acc = {0.f, 0.f, 0.f, 0.f};                                  \
        _Pragma("unroll")                                                   \
        for (int _ks = 0; _ks < 4; ++_ks)                                   \
          _acc = __builtin_amdgcn_mfma_f32_16x16x32_bf16(                   \
              afrag[_rs][_ks], (BF)[_ks], _acc, 0, 0, 0);                   \
        f32x4 _c4 = _acc;                                                   \
        f32x4 _d4 = ki[_rs] - _tj4;                                         \
        f32x4 _m4;                                                          \
        _Pragma("unroll")                                                   \
        for (int _rr = 0; _rr < 4; ++_rr) {                                 \
          bool _q = (__builtin_fabsf(_d4[_rr]) <= 0.1f) &                   \
                    ((ki[_rs][_rr] > 0.0f) == _pj);                         \
          _m4[_rr] = _q ? 1.0f : 0.0f;                                      \
        }                                                                   \
        f32x4 _x4 = _c4 * _K4 - _K4;                                        \
        f32x4 _e4;                                                          \
        _Pragma("unroll")                                                   \
        for (int _rr = 0; _rr < 4; ++_rr)                                   \
          _e4[_rr] = __builtin_amdgcn_exp2f(_x4[_rr]);                      \
        Z[_rs]  += _e4;                                                     \
        Zp[_rs] += _m4 * _e4;                                               \
        Cp[_rs] += _m4 * _c4;                                               \
        Np[_rs] += _m4;                                                     \
      }                                                                     \
    } while (0)

  // ---- main sweep: 32 column-tiles, 2-deep ping-pong prefetch, no barriers ----
  bf16x8 bA[4], bB[4];
  float tjA, tjB;
  LOADB(bA, tjA, 0);
  for (int ct = 0; ct < CT_TOTAL; ct += 2) {
    LOADB(bB, tjB, ct + 1);          // ct+1 <= 31 always inside loop
    COMPUTE(bA, tjA);
    if (ct + 2 < CT_TOTAL) LOADB(bA, tjA, ct + 2);
    COMPUTE(bB, tjB);
  }
  #undef LOADB
  #undef COMPUTE

  // reduce over the 16 lanes (p15) sharing each row
  #pragma unroll
  for (int rs = 0; rs < 4; ++rs) {
    #pragma unroll
    for (int rr = 0; rr < 4; ++rr) {
      #pragma unroll
      for (int off = 1; off < 16; off <<= 1) {
        Z[rs][rr]  += __shfl_xor(Z[rs][rr],  off, 64);
        Zp[rs][rr] += __shfl_xor(Zp[rs][rr], off, 64);
        Cp[rs][rr] += __shfl_xor(Cp[rs][rr], off, 64);
        Np[rs][rr] += __shfl_xor(Np[rs][rr], off, 64);
      }
    }
  }
  if (p15 == 0) {
    #pragma unroll
    for (int rs = 0; rs < 4; ++rs)
      #pragma unroll
      for (int rr = 0; rr < 4; ++rr) {
        size_t row = rbase + rs * 16 + rl4 * 4 + rr;
        f32x4 st = {Z[rs][rr], Zp[rs][rr], Cp[rs][rr], Np[rs][rr]};
        *(f32x4*)&partials[((size_t)row * JCHUNKS + chunk) * 4] = st;
      }
  }
}

// ---------------- kernel 3: per-row loss + global mean (atomic) ----------------
__global__ void finalize_rows(const float* __restrict__ partials,
                              float* __restrict__ out) {
  int r = blockIdx.x * 256 + threadIdx.x;   // grid 32 x 256
  float Z = 0, Zp = 0, Cp = 0, Np = 0;
  for (int ch = 0; ch < JCHUNKS; ++ch) {
    float4 p = *(const float4*)&partials[((size_t)r * JCHUNKS + ch) * 4];
    Z += p.x; Zp += p.y; Cp += p.z; Np += p.w;
  }
  float Zn = Z - Zp;
  float nn = (float)NROWS - Np;
  float spos = (1.0f + logf(Z)) - Cp / Np;
  float sneg = Zn / Z - nn * 1e-10f;
  float per_row = spos + sneg / nn;

  float v = per_row;
  for (int off = 32; off; off >>= 1) v += __shfl_xor(v, off, 64);
  __shared__ float wsum[4];
  int lane = threadIdx.x & 63, wid = threadIdx.x >> 6;
  if (lane == 0) wsum[wid] = v;
  __syncthreads();
  if (threadIdx.x == 0)
    atomicAdd(out, (wsum[0] + wsum[1] + wsum[2] + wsum[3]) * (1.0f / (float)NROWS));
}

// ---------------- launch ----------------
extern "C" void kernel_launch(void* const* d_in, const int* in_sizes, int n_in,
                              void* d_out, int out_size, void* d_ws, size_t ws_size,
                              hipStream_t stream) {
  const float* f1  = (const float*)d_in[0];
  const float* f2  = (const float*)d_in[1];
  const float* tgt = (const float*)d_in[2];
  float* out = (float*)d_out;

  char* ws = (char*)d_ws;
  __hip_bfloat16* f1b = (__hip_bfloat16*)ws;                       // 2 MB
  __hip_bfloat16* f2b = (__hip_bfloat16*)(ws + (size_t)NROWS * DDIM * 2);
  float* partials = (float*)(ws + (size_t)NROWS * DDIM * 4);       // 2 MB

  norm_kernel<<<2 * (NROWS / 8), 256, 0, stream>>>(f1, f2, f1b, f2b, out);
  dim3 g2(GRIDX, JCHUNKS);
  stats_kernel<<<g2, 128, 0, stream>>>(f1b, f2b, tgt, partials);
  finalize_rows<<<NROWS / 256, 256, 0, stream>>>(partials, out);
}